// Round 6
// baseline (1215.953 us; speedup 1.0000x reference)
//
#include <hip/hip_runtime.h>
#include <hip/hip_bf16.h>
#include <math.h>

#define S_TOT 262144   // 64^3
#define EPS_F 1e-5f
#define NPART 1024     // pool partial-K blocks

typedef __attribute__((ext_vector_type(8))) short s16x8;
typedef __attribute__((ext_vector_type(4))) float f32x4;

#define GPLANE 8008    // LDS channel-group plane stride in shorts (16016 B: +16B pad)

__device__ __forceinline__ unsigned short f2bf(float f) {   // RNE, manual
    unsigned u = __builtin_bit_cast(unsigned, f);
    unsigned r = (u + 0x7FFFu + ((u >> 16) & 1u)) >> 16;
    return (unsigned short)r;
}
__device__ __forceinline__ float bf2f(unsigned short u) {
    return __builtin_bit_cast(float, ((unsigned)u) << 16);
}

// ---------------------------------------------------------------------------
// Weight prep: fp32 -> bf16 hi/lo split, layout [layer][tap][hi|lo][brow][cin],
// INTERLEAVED cout mapping: brow(cout) = ((cout&1)<<4) | (cout>>1).
// Layer 0: cin=1 padded to 32 with zeros.
// ---------------------------------------------------------------------------
__global__ __launch_bounds__(256)
void prep_w_k(const float* __restrict__ conv0_w, const float* __restrict__ convs_w,
              unsigned short* __restrict__ wpad)
{
    int idx = blockIdx.x * 256 + threadIdx.x;     // 4*27*32*32 = 110592
    if (idx >= 110592) return;
    int layer = idx / 27648;
    int rem   = idx - layer * 27648;
    int tap   = rem >> 10;
    int cout  = (rem >> 5) & 31;
    int cin   = rem & 31;
    float wv;
    if (layer == 0) wv = (cin == 0) ? conv0_w[cout * 27 + tap] : 0.f;
    else            wv = convs_w[(((layer - 1) * 32 + cout) * 32 + cin) * 27 + tap];
    unsigned short hi = f2bf(wv);
    float hif = bf2f(hi);
    unsigned short lo = f2bf(wv - hif);
    int brow = ((cout & 1) << 4) | (cout >> 1);
    size_t base = ((size_t)(layer * 27 + tap) * 2) * 1024 + brow * 32 + cin;
    wpad[base]        = hi;
    wpad[base + 1024] = lo;
}

// ---------------------------------------------------------------------------
// Pipelined MFMA conv layer. 256 blocks (1/CU), 512 threads (8 waves), each
// block runs 4 consecutive 8x8x8 tiles, double-buffered LDS.
// LDS layout: CHANNEL-MAJOR: buf[g][vox] (g = 8-ch group 0..3, vox 0..999),
// 16B per entry, plane stride GPLANE shorts (16016B, +16B pad -> bank spread).
// MFMA A-read: 16 lanes of a row-group read contiguous 256B -> conflict-free,
// and the fully-unrolled tap loop folds dvox*16 into ds_read imm offsets.
// Output: bf16 channels-last, packed-u32 direct stores.
// ---------------------------------------------------------------------------
template<bool FIRST>
__global__ __launch_bounds__(512, 1)
void conv_pipe_k(const void* __restrict__ in_, const unsigned short* __restrict__ wpad_l,
                 const float* __restrict__ stats_in, unsigned short* __restrict__ outb,
                 float* __restrict__ raw_out)
{
    __shared__ unsigned short buf[2][4 * GPLANE];   // 2 x 64064 B
    __shared__ float s_red[2][512];                 // [pp][wave][cout][sum|sumsq]

    const int tid  = threadIdx.x;
    const int lane = tid & 63;
    const int wv   = tid >> 6;        // wave = z-plane 0..7
    const int row  = lane & 15;
    const int g4   = lane >> 4;
    const int g    = tid & 3;         // staging channel-group
    const int vox0 = tid >> 2;        // 0..127

    const int t40 = blockIdx.x << 2;  // first tile index of this block
    const int b   = t40 >> 9;         // batch (constant across the 4 tiles)

    // per-thread norm constants for staging channel group g
    float rs[8], sh[8];
    if (!FIRST) {
        #pragma unroll
        for (int j = 0; j < 8; ++j) {
            float m = stats_in[(b * 32 + g * 8 + j) * 2];
            float r = stats_in[(b * 32 + g * 8 + j) * 2 + 1];
            rs[j] = r; sh[j] = -m * r;
        }
    }

    int vbase[4];
    #pragma unroll
    for (int f = 0; f < 4; ++f) {
        int vvx = f * 16 + row;
        vbase[f] = wv * 100 + (vvx >> 3) * 10 + (vvx & 7);
    }

    s16x8 pend[8];
    float pendf[8];
    int   okm = 0;

    // ---- issue: global loads for tile k into pend regs (coalesced) ----
    auto issue = [&](int k) {
        int t  = (t40 + k) & 511;
        int x0 = (t & 7) << 3, y0 = ((t >> 3) & 7) << 3, z0 = (t >> 6) << 3;
        okm = 0;
        #pragma unroll
        for (int u = 0; u < 8; ++u) {
            int vox = vox0 + u * 128;
            int zz = vox / 100, r2 = vox - zz * 100, yy = r2 / 10, xx = r2 - yy * 10;
            int gz = z0 + zz - 1, gy = y0 + yy - 1, gx = x0 + xx - 1;
            bool ok = (vox < 1000) && ((unsigned)gz < 64u) && ((unsigned)gy < 64u)
                      && ((unsigned)gx < 64u);
            okm |= ((int)ok) << u;
            if (FIRST) {
                float v = 0.f;
                if (ok && g == 0)
                    v = ((const float*)in_)[((size_t)b << 18) + (gz << 12) + (gy << 6) + gx];
                pendf[u] = v;
            } else {
                s16x8 v = (s16x8)0;
                if (ok)
                    v = *(const s16x8*)((const unsigned short*)in_
                        + ((((size_t)b << 18) + (gz << 12) + (gy << 6) + gx) << 5) + (g << 3));
                pend[u] = v;
            }
        }
    };

    // ---- commit: normalize + ds_write pend into buf[pp] (channel-major) ----
    auto commit = [&](int pp) {
        unsigned short* bp = buf[pp];
        #pragma unroll
        for (int u = 0; u < 8; ++u) {
            int vox = vox0 + u * 128;
            if (vox >= 1000) continue;
            bool ok = (okm >> u) & 1;
            s16x8 vec = (s16x8)0;
            if (FIRST) {
                if (g == 0) vec[0] = (short)f2bf(pendf[u]);
            } else if (ok) {
                #pragma unroll
                for (int j = 0; j < 8; ++j) {
                    float v = bf2f((unsigned short)pend[u][j]);
                    vec[j] = (short)f2bf(fmaxf(0.f, fmaf(v, rs[j], sh[j])));
                }
            }
            *(s16x8*)&bp[g * GPLANE + (vox << 3)] = vec;
        }
    };

    // ================= pipeline =================
    issue(0);
    commit(0);
    __syncthreads();

    int p = 0;
    #pragma unroll 1
    for (int k = 0; k < 4; ++k) {
        if (k < 3) issue(k + 1);

        // ---- MFMA over buf[p]: fully unrolled taps, imm-offset ds_reads ----
        f32x4 acc[4][2] = {};
        {
            const unsigned short* bp = buf[p];
            const unsigned short* a0 = bp + g4 * GPLANE + (vbase[0] << 3);
            const unsigned short* a1 = bp + g4 * GPLANE + (vbase[1] << 3);
            const unsigned short* a2 = bp + g4 * GPLANE + (vbase[2] << 3);
            const unsigned short* a3 = bp + g4 * GPLANE + (vbase[3] << 3);
            const unsigned short* wrow = wpad_l + row * 32 + g4 * 8;

            #pragma unroll
            for (int dz = 0; dz < 3; ++dz) {
                #pragma unroll
                for (int dy = 0; dy < 3; ++dy) {
                    #pragma unroll
                    for (int dx = 0; dx < 3; ++dx) {
                        const int tap  = (dz * 3 + dy) * 3 + dx;
                        const int doff = (dz * 100 + dy * 10 + dx) << 3;   // shorts
                        const unsigned short* wb = wrow + tap * 2048;
                        s16x8 wh0 = *(const s16x8*)(wb);
                        s16x8 wh1 = *(const s16x8*)(wb + 512);
                        s16x8 wl0 = *(const s16x8*)(wb + 1024);
                        s16x8 wl1 = *(const s16x8*)(wb + 1536);
                        s16x8 av0 = *(const s16x8*)(a0 + doff);
                        s16x8 av1 = *(const s16x8*)(a1 + doff);
                        s16x8 av2 = *(const s16x8*)(a2 + doff);
                        s16x8 av3 = *(const s16x8*)(a3 + doff);
                        acc[0][0] = __builtin_amdgcn_mfma_f32_16x16x32_bf16(av0, wh0, acc[0][0], 0, 0, 0);
                        acc[1][0] = __builtin_amdgcn_mfma_f32_16x16x32_bf16(av1, wh0, acc[1][0], 0, 0, 0);
                        acc[2][0] = __builtin_amdgcn_mfma_f32_16x16x32_bf16(av2, wh0, acc[2][0], 0, 0, 0);
                        acc[3][0] = __builtin_amdgcn_mfma_f32_16x16x32_bf16(av3, wh0, acc[3][0], 0, 0, 0);
                        acc[0][1] = __builtin_amdgcn_mfma_f32_16x16x32_bf16(av0, wh1, acc[0][1], 0, 0, 0);
                        acc[1][1] = __builtin_amdgcn_mfma_f32_16x16x32_bf16(av1, wh1, acc[1][1], 0, 0, 0);
                        acc[2][1] = __builtin_amdgcn_mfma_f32_16x16x32_bf16(av2, wh1, acc[2][1], 0, 0, 0);
                        acc[3][1] = __builtin_amdgcn_mfma_f32_16x16x32_bf16(av3, wh1, acc[3][1], 0, 0, 0);
                        acc[0][0] = __builtin_amdgcn_mfma_f32_16x16x32_bf16(av0, wl0, acc[0][0], 0, 0, 0);
                        acc[1][0] = __builtin_amdgcn_mfma_f32_16x16x32_bf16(av1, wl0, acc[1][0], 0, 0, 0);
                        acc[2][0] = __builtin_amdgcn_mfma_f32_16x16x32_bf16(av2, wl0, acc[2][0], 0, 0, 0);
                        acc[3][0] = __builtin_amdgcn_mfma_f32_16x16x32_bf16(av3, wl0, acc[3][0], 0, 0, 0);
                        acc[0][1] = __builtin_amdgcn_mfma_f32_16x16x32_bf16(av0, wl1, acc[0][1], 0, 0, 0);
                        acc[1][1] = __builtin_amdgcn_mfma_f32_16x16x32_bf16(av1, wl1, acc[1][1], 0, 0, 0);
                        acc[2][1] = __builtin_amdgcn_mfma_f32_16x16x32_bf16(av2, wl1, acc[2][1], 0, 0, 0);
                        acc[3][1] = __builtin_amdgcn_mfma_f32_16x16x32_bf16(av3, wl1, acc[3][1], 0, 0, 0);
                    }
                }
            }
        }

        // ---- instance-norm partial stats ----
        {
            float s0 = 0.f, ss0 = 0.f, s1 = 0.f, ss1 = 0.f;
            #pragma unroll
            for (int f = 0; f < 4; ++f) {
                #pragma unroll
                for (int q = 0; q < 4; ++q) {
                    float v0 = acc[f][0][q], v1 = acc[f][1][q];
                    s0 += v0; ss0 += v0 * v0; s1 += v1; ss1 += v1 * v1;
                }
            }
            s0 += __shfl_xor(s0, 16); s0 += __shfl_xor(s0, 32);
            ss0 += __shfl_xor(ss0, 16); ss0 += __shfl_xor(ss0, 32);
            s1 += __shfl_xor(s1, 16); s1 += __shfl_xor(s1, 32);
            ss1 += __shfl_xor(ss1, 16); ss1 += __shfl_xor(ss1, 32);
            if (lane < 16) {
                s_red[p][(wv * 32 + 2 * row) * 2]         = s0;
                s_red[p][(wv * 32 + 2 * row) * 2 + 1]     = ss0;
                s_red[p][(wv * 32 + 2 * row + 1) * 2]     = s1;
                s_red[p][(wv * 32 + 2 * row + 1) * 2 + 1] = ss1;
            }
        }

        // ---- stage next tile into the other buffer ----
        if (k < 3) commit(p ^ 1);

        // ---- direct packed stores (channels-last bf16) ----
        {
            int t  = (t40 + k) & 511;
            int x0 = (t & 7) << 3, y0 = ((t >> 3) & 7) << 3, z0 = (t >> 6) << 3;
            unsigned short* ob = outb
                + ((((size_t)b << 18) + ((size_t)(z0 + wv) << 12) + (y0 << 6) + x0) << 5)
                + (row << 1);
            #pragma unroll
            for (int f = 0; f < 4; ++f) {
                #pragma unroll
                for (int qq = 0; qq < 4; ++qq) {
                    int u = g4 * 4 + qq;
                    int yy = f * 2 + (u >> 3), xx = u & 7;
                    unsigned pk = (unsigned)f2bf(acc[f][0][qq])
                                | ((unsigned)f2bf(acc[f][1][qq]) << 16);
                    *(unsigned*)(ob + ((yy << 6) + xx) * 32) = pk;
                }
            }
        }

        __syncthreads();   // buf[p^1] staged; buf[p] free; s_red[p] complete

        if (tid < 64) {
            int n = tid & 31, sel = tid >> 5;
            float tot = 0.f;
            #pragma unroll
            for (int w = 0; w < 8; ++w) tot += s_red[p][(w * 32 + n) * 2 + sel];
            atomicAdd(&raw_out[(b * 32 + n) * 2 + sel], tot);
        }
        p ^= 1;
    }
}

__global__ void stats_final_k(const float* __restrict__ raw, float* __restrict__ stats)
{
    int bc = threadIdx.x;   // 64
    float mean = raw[bc * 2] * (1.f / 262144.f);
    float var  = raw[bc * 2 + 1] * (1.f / 262144.f) - mean * mean;
    stats[bc * 2]     = mean;
    stats[bc * 2 + 1] = rsqrtf(var + EPS_F);
}

// ---------------------------------------------------------------------------
// Pack 0/1 float mask into bits (u64 per 64 voxels) + per-ROI voxel counts.
// ---------------------------------------------------------------------------
__global__ __launch_bounds__(256)
void pack_mask_k(const float* __restrict__ mask, unsigned long long* __restrict__ bits,
                 float* __restrict__ cnt)
{
    const int r = blockIdx.x >> 4, part = blockIdx.x & 15;
    const int lane = threadIdx.x & 63, wv = threadIdx.x >> 6;
    const size_t base = (size_t)r * S_TOT + part * 16384;
    int local = 0;
    for (int wd = wv; wd < 256; wd += 4) {
        float v = mask[base + wd * 64 + lane];
        unsigned long long bm = __ballot(v != 0.f);
        if (lane == 0) { bits[r * 4096 + part * 256 + wd] = bm; local += __popcll(bm); }
    }
    if (lane == 0) atomicAdd(&cnt[r], (float)local);
}

// ---------------------------------------------------------------------------
// ROI pooling as MFMA GEMM: D[bc=64][r=96] += A[bc][s] * B[s][r]
// A = norm+relu(emb bf16 channels-last), transposed into LDS on load.
// B = mask bits -> bf16.  NPART blocks x 2 chunks x 128 s.
// Dense per-block partial tile store (no atomics) -> part[block][96][64].
// ---------------------------------------------------------------------------
__global__ __launch_bounds__(256)
void pool_mfma_k(const unsigned short* __restrict__ emb, const float* __restrict__ stats3,
                 const unsigned long long* __restrict__ bits, float* __restrict__ part)
{
    __shared__ unsigned short Ald[64 * 136];   // [bc][k=128] bf16
    __shared__ unsigned short Bld[96 * 136];   // [r][k=128] bf16
    __shared__ float s_ns[128];                // rs[64] | -m*rs[64]

    const int tid  = threadIdx.x;
    const int lane = tid & 63, wv = tid >> 6;
    const int row  = lane & 15, g4 = lane >> 4;

    if (tid < 64) {
        float m = stats3[tid * 2], rs = stats3[tid * 2 + 1];
        s_ns[tid]      = rs;
        s_ns[64 + tid] = -m * rs;
    }

    f32x4 acc[6] = {};

    for (int ch = 0; ch < 2; ++ch) {
        const int s0 = (blockIdx.x * 2 + ch) << 7;
        __syncthreads();
        // stage A: channels-last bf16 -> normalized [bc][s] (transpose on load)
        for (int i = tid; i < 1024; i += 256) {
            int bb = i >> 9, v = (i >> 2) & 127, g = i & 3;
            const unsigned short* p = emb + (((size_t)bb << 18) + (size_t)(s0 + v)) * 32 + (g << 3);
            s16x8 rv = *(const s16x8*)p;
            #pragma unroll
            for (int j = 0; j < 8; ++j) {
                int bc = bb * 32 + (g << 3) + j;
                float vf = bf2f((unsigned short)rv[j]);
                float nv = fmaxf(0.f, fmaf(vf, s_ns[bc], s_ns[64 + bc]));
                Ald[bc * 136 + v] = f2bf(nv);
            }
        }
        // stage B: bit-expand mask to bf16 (r >= 90 -> zeros)
        for (int i = tid; i < 1536; i += 256) {
            int r = i >> 4, bs = i & 15;
            s16x8 vec = (s16x8)0;
            if (r < 90) {
                unsigned long long w = bits[r * 4096 + (s0 >> 6) + (bs >> 3)];
                unsigned byte = (unsigned)(w >> ((bs & 7) * 8)) & 0xFFu;
                #pragma unroll
                for (int j = 0; j < 8; ++j)
                    vec[j] = ((byte >> j) & 1u) ? (short)0x3F80 : (short)0;
            }
            *(s16x8*)&Bld[r * 136 + bs * 8] = vec;
        }
        __syncthreads();
        #pragma unroll
        for (int kk = 0; kk < 4; ++kk) {
            s16x8 a = *(const s16x8*)&Ald[(wv * 16 + row) * 136 + kk * 32 + g4 * 8];
            #pragma unroll
            for (int j = 0; j < 6; ++j) {
                s16x8 bb = *(const s16x8*)&Bld[(j * 16 + row) * 136 + kk * 32 + g4 * 8];
                acc[j] = __builtin_amdgcn_mfma_f32_16x16x32_bf16(a, bb, acc[j], 0, 0, 0);
            }
        }
    }
    #pragma unroll
    for (int j = 0; j < 6; ++j) {
        *(f32x4*)&part[((size_t)blockIdx.x * 96 + j * 16 + row) * 64 + wv * 16 + g4 * 4]
            = acc[j];
    }
}

// ---------------------------------------------------------------------------
// Per-ROI partial reduction + gated MLP + projection. One block (64 threads)
// per (b, r).
// ---------------------------------------------------------------------------
__global__ __launch_bounds__(64)
void mlp_k(const float* __restrict__ part, const float* __restrict__ cnt,
           const float* __restrict__ w1, const float* __restrict__ b1,
           const float* __restrict__ w2, const float* __restrict__ b2,
           const float* __restrict__ pw1, const float* __restrict__ pb1,
           const float* __restrict__ pw2, const float* __restrict__ pb2,
           float* __restrict__ out)
{
    const int r   = blockIdx.x % 90;
    const int b   = blockIdx.x / 90;
    const int tid = threadIdx.x;
    __shared__ float roi_s[32], h_s[64], f_s[32], p_s[64];

    {
        const int c = tid & 31, h = tid >> 5;
        const float* pp = part + ((size_t)(h * (NPART / 2)) * 96 + r) * 64 + b * 32 + c;
        float s = 0.f;
        #pragma unroll 4
        for (int p = 0; p < NPART / 2; ++p) s += pp[(size_t)p * 6144];
        s += __shfl_down(s, 32);
        if (tid < 32) roi_s[tid] = s / cnt[r];
    }
    __syncthreads();
    {
        float s = b1[r * 64 + tid];
        for (int c = 0; c < 32; ++c)
            s = fmaf(roi_s[c], w1[(r * 32 + c) * 64 + tid], s);
        h_s[tid] = fmaxf(s, 0.f);
    }
    __syncthreads();
    if (tid < 32) {
        float s = b2[r * 32 + tid];
        for (int j = 0; j < 64; ++j)
            s = fmaf(h_s[j], w2[(r * 64 + j) * 32 + tid], s);
        float gate = 1.f / (1.f + expf(-s));
        f_s[tid] = gate * roi_s[tid];
    }
    __syncthreads();
    {
        float s = pb1[r * 64 + tid];
        for (int c = 0; c < 32; ++c)
            s = fmaf(f_s[c], pw1[(r * 32 + c) * 64 + tid], s);
        p_s[tid] = fmaxf(s, 0.f);
    }
    __syncthreads();
    if (tid < 32) {
        float s = pb2[r * 32 + tid];
        for (int j = 0; j < 64; ++j)
            s = fmaf(p_s[j], pw2[(r * 64 + j) * 32 + tid], s);
        out[((size_t)b * 90 + r) * 32 + tid] = s;
    }
}

// ---------------------------------------------------------------------------
extern "C" void kernel_launch(void* const* d_in, const int* in_sizes, int n_in,
                              void* d_out, int out_size, void* d_ws, size_t ws_size,
                              hipStream_t stream)
{
    const float* data    = (const float*)d_in[0];
    const float* mask    = (const float*)d_in[1];
    const float* conv0_w = (const float*)d_in[2];
    const float* convs_w = (const float*)d_in[4];
    const float* sw1 = (const float*)d_in[6];
    const float* sb1 = (const float*)d_in[7];
    const float* sw2 = (const float*)d_in[8];
    const float* sb2 = (const float*)d_in[9];
    const float* pw1 = (const float*)d_in[10];
    const float* pb1 = (const float*)d_in[11];
    const float* pw2 = (const float*)d_in[12];
    const float* pb2 = (const float*)d_in[13];
    float* out = (float*)d_out;

    float* ws = (float*)d_ws;
    unsigned short* bufA = (unsigned short*)ws;                  // 16,777,216 bf16
    unsigned short* bufB = (unsigned short*)(ws + 8388608);      // 16,777,216 bf16
    unsigned short* wpad = (unsigned short*)(ws + 16777216);     // 221,184 ushort
    float* zeroreg = ws + 16887808;
    float* raw     = zeroreg;            // 512
    float* cnt     = zeroreg + 6272;     // 90
    float* stats   = zeroreg + 6362;     // 512
    unsigned long long* bits = (unsigned long long*)(ws + 16894720);  // 368,640 u64
    float* part    = ws + 17825792;      // NPART*96*64 = 6,291,456 floats (25MB)

    hipMemsetAsync(zeroreg, 0, 6362 * sizeof(float), stream);
    prep_w_k<<<432, 256, 0, stream>>>(conv0_w, convs_w, wpad);

    // layer 0: data(fp32) -> bufA (bf16 channels-last)
    hipLaunchKernelGGL((conv_pipe_k<true>), dim3(256), dim3(512), 0, stream,
                       (const void*)data, wpad, (const float*)nullptr, bufA, raw);
    stats_final_k<<<1, 64, 0, stream>>>(raw, stats);
    // layer 1: bufA -> bufB
    hipLaunchKernelGGL((conv_pipe_k<false>), dim3(256), dim3(512), 0, stream,
                       (const void*)bufA, wpad + 55296, stats, bufB, raw + 128);
    stats_final_k<<<1, 64, 0, stream>>>(raw + 128, stats + 128);
    // layer 2: bufB -> bufA
    hipLaunchKernelGGL((conv_pipe_k<false>), dim3(256), dim3(512), 0, stream,
                       (const void*)bufB, wpad + 2 * 55296, stats + 128, bufA, raw + 256);
    stats_final_k<<<1, 64, 0, stream>>>(raw + 256, stats + 256);
    // layer 3: bufA -> bufB (bf16 channels-last)
    hipLaunchKernelGGL((conv_pipe_k<false>), dim3(256), dim3(512), 0, stream,
                       (const void*)bufA, wpad + 3 * 55296, stats + 256, bufB, raw + 384);
    stats_final_k<<<1, 64, 0, stream>>>(raw + 384, stats + 384);

    // mask -> bits (+counts)
    pack_mask_k<<<1440, 256, 0, stream>>>(mask, bits, cnt);

    // ROI pooling GEMM -> dense partials (no atomics)
    pool_mfma_k<<<NPART, 256, 0, stream>>>(bufB, stats + 384, bits, part);

    // per-ROI partial reduction + MLPs
    mlp_k<<<180, 64, 0, stream>>>(part, cnt, sw1, sb1, sw2, sb2,
                                  pw1, pb1, pw2, pb2, out);
}

// Round 7
// 405.439 us; speedup vs baseline: 2.9991x; 2.9991x over previous
//
#include <hip/hip_runtime.h>
#include <hip/hip_bf16.h>
#include <math.h>

#define S_TOT 262144   // 64^3
#define EPS_F 1e-5f
#define NPART 1024     // pool partial-K blocks
#define PLSTR 14408    // LDS plane stride in shorts (1800 voxels*8 + 8 pad)

typedef __attribute__((ext_vector_type(8))) short s16x8;
typedef __attribute__((ext_vector_type(4))) float f32x4;

__device__ __forceinline__ unsigned short f2bf(float f) {   // RNE, manual
    unsigned u = __builtin_bit_cast(unsigned, f);
    unsigned r = (u + 0x7FFFu + ((u >> 16) & 1u)) >> 16;
    return (unsigned short)r;
}
__device__ __forceinline__ float bf2f(unsigned short u) {
    return __builtin_bit_cast(float, ((unsigned)u) << 16);
}

// ---------------------------------------------------------------------------
// Weight prep: fp32 -> bf16 hi/lo split, layout [layer][tap][hi|lo][brow][cin],
// INTERLEAVED cout mapping: brow(cout) = ((cout&1)<<4) | (cout>>1).
// Layer 0: cin=1 padded to 32 with zeros.
// ---------------------------------------------------------------------------
__global__ __launch_bounds__(256)
void prep_w_k(const float* __restrict__ conv0_w, const float* __restrict__ convs_w,
              unsigned short* __restrict__ wpad)
{
    int idx = blockIdx.x * 256 + threadIdx.x;     // 4*27*32*32 = 110592
    if (idx >= 110592) return;
    int layer = idx / 27648;
    int rem   = idx - layer * 27648;
    int tap   = rem >> 10;
    int cout  = (rem >> 5) & 31;
    int cin   = rem & 31;
    float wv;
    if (layer == 0) wv = (cin == 0) ? conv0_w[cout * 27 + tap] : 0.f;
    else            wv = convs_w[(((layer - 1) * 32 + cout) * 32 + cin) * 27 + tap];
    unsigned short hi = f2bf(wv);
    float hif = bf2f(hi);
    unsigned short lo = f2bf(wv - hif);
    int brow = ((cout & 1) << 4) | (cout >> 1);
    size_t base = ((size_t)(layer * 27 + tap) * 2) * 1024 + brow * 32 + cin;
    wpad[base]        = hi;
    wpad[base + 1024] = lo;
}

// ---------------------------------------------------------------------------
// MFMA conv layer, 8x8x16 slab per block. 512 blocks, 512 threads (8 waves),
// wave wv owns z-planes {2wv, 2wv+1}.  LDS: channel-major 4 planes of 1800
// halo voxels x 16B (plane stride PLSTR shorts) -> A-reads conflict-free.
// Rolled dz/dy/dx tap loops (bounded VGPR, no spills); 8 ds_read_b128 +
// 4 weight loads + 32 MFMA per tap.  Output: bf16 channels-last packed-u32
// direct stores (full-line coverage).  Stats fused via shfl+LDS+atomics.
// ---------------------------------------------------------------------------
template<bool FIRST>
__global__ __launch_bounds__(512, 2)
void conv_slab_k(const void* __restrict__ in_, const unsigned short* __restrict__ wpad_l,
                 const float* __restrict__ stats_in, unsigned short* __restrict__ outb,
                 float* __restrict__ raw_out)
{
    __shared__ unsigned short tile[4 * PLSTR];   // 115,264 B
    __shared__ float s_red[512];                 // [wave][cout][sum|sumsq]

    const int tid  = threadIdx.x;
    const int lane = tid & 63;
    const int wv   = tid >> 6;        // wave 0..7
    const int row  = lane & 15;
    const int g4   = lane >> 4;
    const int g    = tid & 3;         // staging channel-group
    const int vox0 = tid >> 2;        // 0..127

    const int blk = blockIdx.x;
    const int b   = blk >> 8;
    const int t   = blk & 255;
    const int x0  = (t & 7) << 3;
    const int y0  = ((t >> 3) & 7) << 3;
    const int z0  = (t >> 6) << 4;    // 4 z-slabs of 16

    // ---- stage halo slab (norm+relu fused for mid layers) ----
    if (FIRST) {
        const float* in = (const float*)in_;
        #pragma unroll 1
        for (int u = 0; u < 15; ++u) {
            int vox = vox0 + u * 128;
            if (vox >= 1800) break;
            s16x8 vec = (s16x8)0;
            if (g == 0) {
                int zz = vox / 100, r2 = vox - zz * 100, yy = r2 / 10, xx = r2 - yy * 10;
                int gz = z0 + zz - 1, gy = y0 + yy - 1, gx = x0 + xx - 1;
                float v = 0.f;
                if ((unsigned)gz < 64u && (unsigned)gy < 64u && (unsigned)gx < 64u)
                    v = in[((size_t)b << 18) + (gz << 12) + (gy << 6) + gx];
                vec[0] = (short)f2bf(v);
            }
            *(s16x8*)&tile[g * PLSTR + (vox << 3)] = vec;
        }
    } else {
        float rs[8], sh[8];
        #pragma unroll
        for (int j = 0; j < 8; ++j) {
            float m = stats_in[(b * 32 + g * 8 + j) * 2];
            float r = stats_in[(b * 32 + g * 8 + j) * 2 + 1];
            rs[j] = r; sh[j] = -m * r;
        }
        const unsigned short* in = (const unsigned short*)in_;
        #pragma unroll 1
        for (int u = 0; u < 15; ++u) {
            int vox = vox0 + u * 128;
            if (vox >= 1800) break;
            int zz = vox / 100, r2 = vox - zz * 100, yy = r2 / 10, xx = r2 - yy * 10;
            int gz = z0 + zz - 1, gy = y0 + yy - 1, gx = x0 + xx - 1;
            s16x8 vec = (s16x8)0;
            if ((unsigned)gz < 64u && (unsigned)gy < 64u && (unsigned)gx < 64u) {
                s16x8 rv = *(const s16x8*)(in
                    + ((((size_t)b << 18) + (gz << 12) + (gy << 6) + gx) << 5) + (g << 3));
                #pragma unroll
                for (int j = 0; j < 8; ++j) {
                    float v = bf2f((unsigned short)rv[j]);
                    vec[j] = (short)f2bf(fmaxf(0.f, fmaf(v, rs[j], sh[j])));
                }
            }
            *(s16x8*)&tile[g * PLSTR + (vox << 3)] = vec;
        }
    }
    __syncthreads();

    // ---- MFMA main loop: rolled taps, channel-major A reads ----
    f32x4 acc[2][4][2] = {};
    {
        const unsigned short* aplane = &tile[g4 * PLSTR];
        int abase[2][4];
        #pragma unroll
        for (int pl = 0; pl < 2; ++pl)
            #pragma unroll
            for (int f = 0; f < 4; ++f) {
                int vvx = f * 16 + row;
                abase[pl][f] = (((2 * wv + pl) * 100 + (vvx >> 3) * 10 + (vvx & 7)) << 3);
            }
        const unsigned short* wrow = wpad_l + row * 32 + g4 * 8;

        #pragma unroll 1
        for (int dz = 0; dz < 3; ++dz) {
            #pragma unroll 1
            for (int dy = 0; dy < 3; ++dy) {
                #pragma unroll 1
                for (int dx = 0; dx < 3; ++dx) {
                    const int tap  = (dz * 3 + dy) * 3 + dx;
                    const int doff = ((dz * 100 + dy * 10 + dx) << 3);
                    const unsigned short* wb = wrow + tap * 2048;
                    s16x8 wh0 = *(const s16x8*)(wb);
                    s16x8 wh1 = *(const s16x8*)(wb + 512);
                    s16x8 wl0 = *(const s16x8*)(wb + 1024);
                    s16x8 wl1 = *(const s16x8*)(wb + 1536);
                    #pragma unroll
                    for (int pl = 0; pl < 2; ++pl) {
                        #pragma unroll
                        for (int f = 0; f < 4; ++f) {
                            s16x8 a = *(const s16x8*)&aplane[abase[pl][f] + doff];
                            acc[pl][f][0] = __builtin_amdgcn_mfma_f32_16x16x32_bf16(a, wh0, acc[pl][f][0], 0, 0, 0);
                            acc[pl][f][0] = __builtin_amdgcn_mfma_f32_16x16x32_bf16(a, wl0, acc[pl][f][0], 0, 0, 0);
                            acc[pl][f][1] = __builtin_amdgcn_mfma_f32_16x16x32_bf16(a, wh1, acc[pl][f][1], 0, 0, 0);
                            acc[pl][f][1] = __builtin_amdgcn_mfma_f32_16x16x32_bf16(a, wl1, acc[pl][f][1], 0, 0, 0);
                        }
                    }
                }
            }
        }
    }

    // ---- instance-norm partial stats (sum over both planes) ----
    {
        float s0 = 0.f, ss0 = 0.f, s1 = 0.f, ss1 = 0.f;
        #pragma unroll
        for (int pl = 0; pl < 2; ++pl)
            #pragma unroll
            for (int f = 0; f < 4; ++f)
                #pragma unroll
                for (int q = 0; q < 4; ++q) {
                    float v0 = acc[pl][f][0][q], v1 = acc[pl][f][1][q];
                    s0 += v0; ss0 += v0 * v0; s1 += v1; ss1 += v1 * v1;
                }
        s0 += __shfl_xor(s0, 16); s0 += __shfl_xor(s0, 32);
        ss0 += __shfl_xor(ss0, 16); ss0 += __shfl_xor(ss0, 32);
        s1 += __shfl_xor(s1, 16); s1 += __shfl_xor(s1, 32);
        ss1 += __shfl_xor(ss1, 16); ss1 += __shfl_xor(ss1, 32);
        if (lane < 16) {
            s_red[(wv * 32 + 2 * row) * 2]         = s0;
            s_red[(wv * 32 + 2 * row) * 2 + 1]     = ss0;
            s_red[(wv * 32 + 2 * row + 1) * 2]     = s1;
            s_red[(wv * 32 + 2 * row + 1) * 2 + 1] = ss1;
        }
    }

    // ---- direct packed stores (channels-last bf16) ----
    #pragma unroll
    for (int pl = 0; pl < 2; ++pl) {
        int zp = 2 * wv + pl;
        unsigned short* ob = outb
            + ((((size_t)b << 18) + ((size_t)(z0 + zp) << 12) + (y0 << 6) + x0) << 5)
            + (row << 1);
        #pragma unroll
        for (int f = 0; f < 4; ++f) {
            #pragma unroll
            for (int qq = 0; qq < 4; ++qq) {
                int u = g4 * 4 + qq;
                int yy = f * 2 + (u >> 3), xx = u & 7;
                unsigned pk = (unsigned)f2bf(acc[pl][f][0][qq])
                            | ((unsigned)f2bf(acc[pl][f][1][qq]) << 16);
                *(unsigned*)(ob + ((yy << 6) + xx) * 32) = pk;
            }
        }
    }

    __syncthreads();
    if (tid < 64) {
        int n = tid & 31, sel = tid >> 5;
        float tot = 0.f;
        #pragma unroll
        for (int w = 0; w < 8; ++w) tot += s_red[(w * 32 + n) * 2 + sel];
        atomicAdd(&raw_out[(b * 32 + n) * 2 + sel], tot);
    }
}

__global__ void stats_final_k(const float* __restrict__ raw, float* __restrict__ stats)
{
    int bc = threadIdx.x;   // 64
    float mean = raw[bc * 2] * (1.f / 262144.f);
    float var  = raw[bc * 2 + 1] * (1.f / 262144.f) - mean * mean;
    stats[bc * 2]     = mean;
    stats[bc * 2 + 1] = rsqrtf(var + EPS_F);
}

// ---------------------------------------------------------------------------
// Pack 0/1 float mask into bits (u64 per 64 voxels) + per-ROI voxel counts.
// ---------------------------------------------------------------------------
__global__ __launch_bounds__(256)
void pack_mask_k(const float* __restrict__ mask, unsigned long long* __restrict__ bits,
                 float* __restrict__ cnt)
{
    const int r = blockIdx.x >> 4, part = blockIdx.x & 15;
    const int lane = threadIdx.x & 63, wv = threadIdx.x >> 6;
    const size_t base = (size_t)r * S_TOT + part * 16384;
    int local = 0;
    for (int wd = wv; wd < 256; wd += 4) {
        float v = mask[base + wd * 64 + lane];
        unsigned long long bm = __ballot(v != 0.f);
        if (lane == 0) { bits[r * 4096 + part * 256 + wd] = bm; local += __popcll(bm); }
    }
    if (lane == 0) atomicAdd(&cnt[r], (float)local);
}

// ---------------------------------------------------------------------------
// ROI pooling as MFMA GEMM: D[bc=64][r=96] += A[bc][s] * B[s][r]
// A = norm+relu(emb bf16 channels-last), transposed into LDS on load.
// B = mask bits -> bf16.  NPART blocks x 2 chunks x 128 s.
// Dense per-block partial tile store (no atomics) -> part[block][96][64].
// ---------------------------------------------------------------------------
__global__ __launch_bounds__(256)
void pool_mfma_k(const unsigned short* __restrict__ emb, const float* __restrict__ stats3,
                 const unsigned long long* __restrict__ bits, float* __restrict__ part)
{
    __shared__ unsigned short Ald[64 * 136];   // [bc][k=128] bf16
    __shared__ unsigned short Bld[96 * 136];   // [r][k=128] bf16
    __shared__ float s_ns[128];                // rs[64] | -m*rs[64]

    const int tid  = threadIdx.x;
    const int lane = tid & 63, wv = tid >> 6;
    const int row  = lane & 15, g4 = lane >> 4;

    if (tid < 64) {
        float m = stats3[tid * 2], rs = stats3[tid * 2 + 1];
        s_ns[tid]      = rs;
        s_ns[64 + tid] = -m * rs;
    }

    f32x4 acc[6] = {};

    for (int ch = 0; ch < 2; ++ch) {
        const int s0 = (blockIdx.x * 2 + ch) << 7;
        __syncthreads();
        // stage A: channels-last bf16 -> normalized [bc][s] (transpose on load)
        for (int i = tid; i < 1024; i += 256) {
            int bb = i >> 9, v = (i >> 2) & 127, g = i & 3;
            const unsigned short* p = emb + (((size_t)bb << 18) + (size_t)(s0 + v)) * 32 + (g << 3);
            s16x8 rv = *(const s16x8*)p;
            #pragma unroll
            for (int j = 0; j < 8; ++j) {
                int bc = bb * 32 + (g << 3) + j;
                float vf = bf2f((unsigned short)rv[j]);
                float nv = fmaxf(0.f, fmaf(vf, s_ns[bc], s_ns[64 + bc]));
                Ald[bc * 136 + v] = f2bf(nv);
            }
        }
        // stage B: bit-expand mask to bf16 (r >= 90 -> zeros)
        for (int i = tid; i < 1536; i += 256) {
            int r = i >> 4, bs = i & 15;
            s16x8 vec = (s16x8)0;
            if (r < 90) {
                unsigned long long w = bits[r * 4096 + (s0 >> 6) + (bs >> 3)];
                unsigned byte = (unsigned)(w >> ((bs & 7) * 8)) & 0xFFu;
                #pragma unroll
                for (int j = 0; j < 8; ++j)
                    vec[j] = ((byte >> j) & 1u) ? (short)0x3F80 : (short)0;
            }
            *(s16x8*)&Bld[r * 136 + bs * 8] = vec;
        }
        __syncthreads();
        #pragma unroll
        for (int kk = 0; kk < 4; ++kk) {
            s16x8 a = *(const s16x8*)&Ald[(wv * 16 + row) * 136 + kk * 32 + g4 * 8];
            #pragma unroll
            for (int j = 0; j < 6; ++j) {
                s16x8 bb = *(const s16x8*)&Bld[(j * 16 + row) * 136 + kk * 32 + g4 * 8];
                acc[j] = __builtin_amdgcn_mfma_f32_16x16x32_bf16(a, bb, acc[j], 0, 0, 0);
            }
        }
    }
    #pragma unroll
    for (int j = 0; j < 6; ++j) {
        *(f32x4*)&part[((size_t)blockIdx.x * 96 + j * 16 + row) * 64 + wv * 16 + g4 * 4]
            = acc[j];
    }
}

// ---------------------------------------------------------------------------
// Per-ROI partial reduction + gated MLP + projection. One block (64 threads)
// per (b, r).
// ---------------------------------------------------------------------------
__global__ __launch_bounds__(64)
void mlp_k(const float* __restrict__ part, const float* __restrict__ cnt,
           const float* __restrict__ w1, const float* __restrict__ b1,
           const float* __restrict__ w2, const float* __restrict__ b2,
           const float* __restrict__ pw1, const float* __restrict__ pb1,
           const float* __restrict__ pw2, const float* __restrict__ pb2,
           float* __restrict__ out)
{
    const int r   = blockIdx.x % 90;
    const int b   = blockIdx.x / 90;
    const int tid = threadIdx.x;
    __shared__ float roi_s[32], h_s[64], f_s[32], p_s[64];

    {
        const int c = tid & 31, h = tid >> 5;
        const float* pp = part + ((size_t)(h * (NPART / 2)) * 96 + r) * 64 + b * 32 + c;
        float s = 0.f;
        #pragma unroll 4
        for (int p = 0; p < NPART / 2; ++p) s += pp[(size_t)p * 6144];
        s += __shfl_down(s, 32);
        if (tid < 32) roi_s[tid] = s / cnt[r];
    }
    __syncthreads();
    {
        float s = b1[r * 64 + tid];
        for (int c = 0; c < 32; ++c)
            s = fmaf(roi_s[c], w1[(r * 32 + c) * 64 + tid], s);
        h_s[tid] = fmaxf(s, 0.f);
    }
    __syncthreads();
    if (tid < 32) {
        float s = b2[r * 32 + tid];
        for (int j = 0; j < 64; ++j)
            s = fmaf(h_s[j], w2[(r * 64 + j) * 32 + tid], s);
        float gate = 1.f / (1.f + expf(-s));
        f_s[tid] = gate * roi_s[tid];
    }
    __syncthreads();
    {
        float s = pb1[r * 64 + tid];
        for (int c = 0; c < 32; ++c)
            s = fmaf(f_s[c], pw1[(r * 32 + c) * 64 + tid], s);
        p_s[tid] = fmaxf(s, 0.f);
    }
    __syncthreads();
    if (tid < 32) {
        float s = pb2[r * 32 + tid];
        for (int j = 0; j < 64; ++j)
            s = fmaf(p_s[j], pw2[(r * 64 + j) * 32 + tid], s);
        out[((size_t)b * 90 + r) * 32 + tid] = s;
    }
}

// ---------------------------------------------------------------------------
extern "C" void kernel_launch(void* const* d_in, const int* in_sizes, int n_in,
                              void* d_out, int out_size, void* d_ws, size_t ws_size,
                              hipStream_t stream)
{
    const float* data    = (const float*)d_in[0];
    const float* mask    = (const float*)d_in[1];
    const float* conv0_w = (const float*)d_in[2];
    const float* convs_w = (const float*)d_in[4];
    const float* sw1 = (const float*)d_in[6];
    const float* sb1 = (const float*)d_in[7];
    const float* sw2 = (const float*)d_in[8];
    const float* sb2 = (const float*)d_in[9];
    const float* pw1 = (const float*)d_in[10];
    const float* pb1 = (const float*)d_in[11];
    const float* pw2 = (const float*)d_in[12];
    const float* pb2 = (const float*)d_in[13];
    float* out = (float*)d_out;

    float* ws = (float*)d_ws;
    unsigned short* bufA = (unsigned short*)ws;                  // 16,777,216 bf16
    unsigned short* bufB = (unsigned short*)(ws + 8388608);      // 16,777,216 bf16
    unsigned short* wpad = (unsigned short*)(ws + 16777216);     // 221,184 ushort
    float* zeroreg = ws + 16887808;
    float* raw     = zeroreg;            // 512
    float* cnt     = zeroreg + 6272;     // 90
    float* stats   = zeroreg + 6362;     // 512
    unsigned long long* bits = (unsigned long long*)(ws + 16894720);  // 368,640 u64
    float* part    = ws + 17825792;      // NPART*96*64 = 6,291,456 floats (25MB)

    hipMemsetAsync(zeroreg, 0, 6362 * sizeof(float), stream);
    prep_w_k<<<432, 256, 0, stream>>>(conv0_w, convs_w, wpad);

    // layer 0: data(fp32) -> bufA (bf16 channels-last)
    hipLaunchKernelGGL((conv_slab_k<true>), dim3(512), dim3(512), 0, stream,
                       (const void*)data, wpad, (const float*)nullptr, bufA, raw);
    stats_final_k<<<1, 64, 0, stream>>>(raw, stats);
    // layer 1: bufA -> bufB
    hipLaunchKernelGGL((conv_slab_k<false>), dim3(512), dim3(512), 0, stream,
                       (const void*)bufA, wpad + 55296, stats, bufB, raw + 128);
    stats_final_k<<<1, 64, 0, stream>>>(raw + 128, stats + 128);
    // layer 2: bufB -> bufA
    hipLaunchKernelGGL((conv_slab_k<false>), dim3(512), dim3(512), 0, stream,
                       (const void*)bufB, wpad + 2 * 55296, stats + 128, bufA, raw + 256);
    stats_final_k<<<1, 64, 0, stream>>>(raw + 256, stats + 256);
    // layer 3: bufA -> bufB (bf16 channels-last)
    hipLaunchKernelGGL((conv_slab_k<false>), dim3(512), dim3(512), 0, stream,
                       (const void*)bufA, wpad + 3 * 55296, stats + 256, bufB, raw + 384);
    stats_final_k<<<1, 64, 0, stream>>>(raw + 384, stats + 384);

    // mask -> bits (+counts)
    pack_mask_k<<<1440, 256, 0, stream>>>(mask, bits, cnt);

    // ROI pooling GEMM -> dense partials (no atomics)
    pool_mfma_k<<<NPART, 256, 0, stream>>>(bufB, stats + 384, bits, part);

    // per-ROI partial reduction + MLPs
    mlp_k<<<180, 64, 0, stream>>>(part, cnt, sw1, sb1, sw2, sb2,
                                  pw1, pb1, pw2, pb2, out);
}

// Round 8
// 297.273 us; speedup vs baseline: 4.0904x; 1.3639x over previous
//
#include <hip/hip_runtime.h>
#include <hip/hip_bf16.h>
#include <math.h>

#define S_TOT 262144   // 64^3
#define EPS_F 1e-5f
#define NPART 512      // pool partial-K blocks
#define PLSTR 14408    // LDS plane stride in shorts (1800 voxels*8 + 8 pad)

typedef __attribute__((ext_vector_type(8))) short s16x8;
typedef __attribute__((ext_vector_type(4))) float f32x4;

__device__ __forceinline__ unsigned short f2bf(float f) {   // RNE, manual
    unsigned u = __builtin_bit_cast(unsigned, f);
    unsigned r = (u + 0x7FFFu + ((u >> 16) & 1u)) >> 16;
    return (unsigned short)r;
}
__device__ __forceinline__ float bf2f(unsigned short u) {
    return __builtin_bit_cast(float, ((unsigned)u) << 16);
}

// ---------------------------------------------------------------------------
// Weight prep.
// Layer 0 (im2col-over-taps): w0[hi|lo][brow][k=tap(32,pad0)] at wpad[0..2047].
// Layers 1-3: [layer][tap][hi|lo][brow][cin] at wpad + layer*55296 (as before).
// brow(cout) = ((cout&1)<<4) | (cout>>1);  cout(brow) = 2*(brow&15)+(brow>>4).
// ---------------------------------------------------------------------------
__global__ __launch_bounds__(256)
void prep_w_k(const float* __restrict__ conv0_w, const float* __restrict__ convs_w,
              unsigned short* __restrict__ wpad)
{
    int idx = blockIdx.x * 256 + threadIdx.x;     // 2048 + 3*27648 = 84992
    if (idx < 2048) {
        int brow = idx >> 5, k = idx & 31;
        int cout = 2 * (brow & 15) + (brow >> 4);
        float wv = (k < 27) ? conv0_w[cout * 27 + k] : 0.f;
        unsigned short hi = f2bf(wv);
        unsigned short lo = f2bf(wv - bf2f(hi));
        wpad[brow * 32 + k]        = hi;
        wpad[1024 + brow * 32 + k] = lo;
        return;
    }
    int j = idx - 2048;
    if (j >= 3 * 27648) return;
    int layer = j / 27648 + 1;
    int rem   = j % 27648;
    int tap   = rem >> 10;
    int cout  = (rem >> 5) & 31;
    int cin   = rem & 31;
    float wv = convs_w[(((layer - 1) * 32 + cout) * 32 + cin) * 27 + tap];
    unsigned short hi = f2bf(wv);
    unsigned short lo = f2bf(wv - bf2f(hi));
    int brow = ((cout & 1) << 4) | (cout >> 1);
    size_t base = ((size_t)(layer * 27 + tap) * 2) * 1024 + brow * 32 + cin;
    wpad[base]        = hi;
    wpad[base + 1024] = lo;
}

// ---------------------------------------------------------------------------
// Layer 0: cin=1 -> im2col over taps (K = 27 taps padded to 32).
// 512 blocks (8x8x16 slab), 512 threads, wave wv owns z-planes {2wv,2wv+1}.
// Scalar bf16 halo tile (1800 shorts).  A-frag: 8 ds_read_u16 gathers.
// 32 MFMAs total per wave.  Epilogue identical to conv_slab_k.
// ---------------------------------------------------------------------------
__global__ __launch_bounds__(512, 2)
void conv0_k(const float* __restrict__ in, const unsigned short* __restrict__ w0,
             unsigned short* __restrict__ outb, float* __restrict__ raw_out)
{
    __shared__ unsigned short sc[1824];
    __shared__ float s_red[512];

    const int tid  = threadIdx.x;
    const int lane = tid & 63;
    const int wv   = tid >> 6;
    const int row  = lane & 15;
    const int g4   = lane >> 4;

    const int blk = blockIdx.x;
    const int b   = blk >> 8;
    const int t   = blk & 255;
    const int x0  = (t & 7) << 3;
    const int y0  = ((t >> 3) & 7) << 3;
    const int z0  = (t >> 6) << 4;

    for (int i = tid; i < 1800; i += 512) {
        int zz = i / 100, r2 = i - zz * 100, yy = r2 / 10, xx = r2 - yy * 10;
        int gz = z0 + zz - 1, gy = y0 + yy - 1, gx = x0 + xx - 1;
        float v = 0.f;
        if ((unsigned)gz < 64u && (unsigned)gy < 64u && (unsigned)gx < 64u)
            v = in[((size_t)b << 18) + (gz << 12) + (gy << 6) + gx];
        sc[i] = f2bf(v);
    }
    __syncthreads();

    // per-lane tap offsets for k = g4*8 + j
    int dvox[8];
    #pragma unroll
    for (int j = 0; j < 8; ++j) {
        int tap = g4 * 8 + j;
        if (tap < 27) {
            int dz = tap / 9, r9 = tap - dz * 9, dy = r9 / 3, dx = r9 - dy * 3;
            dvox[j] = dz * 100 + dy * 10 + dx;
        } else dvox[j] = 0;
    }

    s16x8 wh0 = *(const s16x8*)(w0 + row * 32 + g4 * 8);
    s16x8 wh1 = *(const s16x8*)(w0 + (16 + row) * 32 + g4 * 8);
    s16x8 wl0 = *(const s16x8*)(w0 + 1024 + row * 32 + g4 * 8);
    s16x8 wl1 = *(const s16x8*)(w0 + 1024 + (16 + row) * 32 + g4 * 8);

    f32x4 acc[2][4][2] = {};
    #pragma unroll
    for (int pl = 0; pl < 2; ++pl) {
        #pragma unroll
        for (int f = 0; f < 4; ++f) {
            int vvx = f * 16 + row;
            int base = (2 * wv + pl) * 100 + (vvx >> 3) * 10 + (vvx & 7);
            s16x8 a;
            #pragma unroll
            for (int j = 0; j < 8; ++j) a[j] = (short)sc[base + dvox[j]];
            acc[pl][f][0] = __builtin_amdgcn_mfma_f32_16x16x32_bf16(a, wh0, acc[pl][f][0], 0, 0, 0);
            acc[pl][f][0] = __builtin_amdgcn_mfma_f32_16x16x32_bf16(a, wl0, acc[pl][f][0], 0, 0, 0);
            acc[pl][f][1] = __builtin_amdgcn_mfma_f32_16x16x32_bf16(a, wh1, acc[pl][f][1], 0, 0, 0);
            acc[pl][f][1] = __builtin_amdgcn_mfma_f32_16x16x32_bf16(a, wl1, acc[pl][f][1], 0, 0, 0);
        }
    }

    // ---- stats ----
    {
        float s0 = 0.f, ss0 = 0.f, s1 = 0.f, ss1 = 0.f;
        #pragma unroll
        for (int pl = 0; pl < 2; ++pl)
            #pragma unroll
            for (int f = 0; f < 4; ++f)
                #pragma unroll
                for (int q = 0; q < 4; ++q) {
                    float v0 = acc[pl][f][0][q], v1 = acc[pl][f][1][q];
                    s0 += v0; ss0 += v0 * v0; s1 += v1; ss1 += v1 * v1;
                }
        s0 += __shfl_xor(s0, 16); s0 += __shfl_xor(s0, 32);
        ss0 += __shfl_xor(ss0, 16); ss0 += __shfl_xor(ss0, 32);
        s1 += __shfl_xor(s1, 16); s1 += __shfl_xor(s1, 32);
        ss1 += __shfl_xor(ss1, 16); ss1 += __shfl_xor(ss1, 32);
        if (lane < 16) {
            s_red[(wv * 32 + 2 * row) * 2]         = s0;
            s_red[(wv * 32 + 2 * row) * 2 + 1]     = ss0;
            s_red[(wv * 32 + 2 * row + 1) * 2]     = s1;
            s_red[(wv * 32 + 2 * row + 1) * 2 + 1] = ss1;
        }
    }

    // ---- direct packed stores ----
    #pragma unroll
    for (int pl = 0; pl < 2; ++pl) {
        int zp = 2 * wv + pl;
        unsigned short* ob = outb
            + ((((size_t)b << 18) + ((size_t)(z0 + zp) << 12) + (y0 << 6) + x0) << 5)
            + (row << 1);
        #pragma unroll
        for (int f = 0; f < 4; ++f) {
            #pragma unroll
            for (int qq = 0; qq < 4; ++qq) {
                int u = g4 * 4 + qq;
                int yy = f * 2 + (u >> 3), xx = u & 7;
                unsigned pk = (unsigned)f2bf(acc[pl][f][0][qq])
                            | ((unsigned)f2bf(acc[pl][f][1][qq]) << 16);
                *(unsigned*)(ob + ((yy << 6) + xx) * 32) = pk;
            }
        }
    }

    __syncthreads();
    if (tid < 64) {
        int n = tid & 31, sel = tid >> 5;
        float tot = 0.f;
        #pragma unroll
        for (int w = 0; w < 8; ++w) tot += s_red[(w * 32 + n) * 2 + sel];
        atomicAdd(&raw_out[(b * 32 + n) * 2 + sel], tot);
    }
}

// ---------------------------------------------------------------------------
// Mid conv layers (unchanged from R7): 8x8x16 slab, channel-major LDS,
// rolled taps, fused norm+relu on load, bf16 channels-last packed stores.
// ---------------------------------------------------------------------------
__global__ __launch_bounds__(512, 2)
void conv_slab_k(const unsigned short* __restrict__ in, const unsigned short* __restrict__ wpad_l,
                 const float* __restrict__ stats_in, unsigned short* __restrict__ outb,
                 float* __restrict__ raw_out)
{
    __shared__ unsigned short tile[4 * PLSTR];   // 115,264 B
    __shared__ float s_red[512];

    const int tid  = threadIdx.x;
    const int lane = tid & 63;
    const int wv   = tid >> 6;
    const int row  = lane & 15;
    const int g4   = lane >> 4;
    const int g    = tid & 3;
    const int vox0 = tid >> 2;

    const int blk = blockIdx.x;
    const int b   = blk >> 8;
    const int t   = blk & 255;
    const int x0  = (t & 7) << 3;
    const int y0  = ((t >> 3) & 7) << 3;
    const int z0  = (t >> 6) << 4;

    {
        float rs[8], sh[8];
        #pragma unroll
        for (int j = 0; j < 8; ++j) {
            float m = stats_in[(b * 32 + g * 8 + j) * 2];
            float r = stats_in[(b * 32 + g * 8 + j) * 2 + 1];
            rs[j] = r; sh[j] = -m * r;
        }
        #pragma unroll 1
        for (int u = 0; u < 15; ++u) {
            int vox = vox0 + u * 128;
            if (vox >= 1800) break;
            int zz = vox / 100, r2 = vox - zz * 100, yy = r2 / 10, xx = r2 - yy * 10;
            int gz = z0 + zz - 1, gy = y0 + yy - 1, gx = x0 + xx - 1;
            s16x8 vec = (s16x8)0;
            if ((unsigned)gz < 64u && (unsigned)gy < 64u && (unsigned)gx < 64u) {
                s16x8 rv = *(const s16x8*)(in
                    + ((((size_t)b << 18) + (gz << 12) + (gy << 6) + gx) << 5) + (g << 3));
                #pragma unroll
                for (int j = 0; j < 8; ++j) {
                    float v = bf2f((unsigned short)rv[j]);
                    vec[j] = (short)f2bf(fmaxf(0.f, fmaf(v, rs[j], sh[j])));
                }
            }
            *(s16x8*)&tile[g * PLSTR + (vox << 3)] = vec;
        }
    }
    __syncthreads();

    f32x4 acc[2][4][2] = {};
    {
        const unsigned short* aplane = &tile[g4 * PLSTR];
        int abase[2][4];
        #pragma unroll
        for (int pl = 0; pl < 2; ++pl)
            #pragma unroll
            for (int f = 0; f < 4; ++f) {
                int vvx = f * 16 + row;
                abase[pl][f] = (((2 * wv + pl) * 100 + (vvx >> 3) * 10 + (vvx & 7)) << 3);
            }
        const unsigned short* wrow = wpad_l + row * 32 + g4 * 8;

        #pragma unroll 1
        for (int dz = 0; dz < 3; ++dz) {
            #pragma unroll 1
            for (int dy = 0; dy < 3; ++dy) {
                #pragma unroll 1
                for (int dx = 0; dx < 3; ++dx) {
                    const int tap  = (dz * 3 + dy) * 3 + dx;
                    const int doff = ((dz * 100 + dy * 10 + dx) << 3);
                    const unsigned short* wb = wrow + tap * 2048;
                    s16x8 wh0 = *(const s16x8*)(wb);
                    s16x8 wh1 = *(const s16x8*)(wb + 512);
                    s16x8 wl0 = *(const s16x8*)(wb + 1024);
                    s16x8 wl1 = *(const s16x8*)(wb + 1536);
                    #pragma unroll
                    for (int pl = 0; pl < 2; ++pl) {
                        #pragma unroll
                        for (int f = 0; f < 4; ++f) {
                            s16x8 a = *(const s16x8*)&aplane[abase[pl][f] + doff];
                            acc[pl][f][0] = __builtin_amdgcn_mfma_f32_16x16x32_bf16(a, wh0, acc[pl][f][0], 0, 0, 0);
                            acc[pl][f][0] = __builtin_amdgcn_mfma_f32_16x16x32_bf16(a, wl0, acc[pl][f][0], 0, 0, 0);
                            acc[pl][f][1] = __builtin_amdgcn_mfma_f32_16x16x32_bf16(a, wh1, acc[pl][f][1], 0, 0, 0);
                            acc[pl][f][1] = __builtin_amdgcn_mfma_f32_16x16x32_bf16(a, wl1, acc[pl][f][1], 0, 0, 0);
                        }
                    }
                }
            }
        }
    }

    {
        float s0 = 0.f, ss0 = 0.f, s1 = 0.f, ss1 = 0.f;
        #pragma unroll
        for (int pl = 0; pl < 2; ++pl)
            #pragma unroll
            for (int f = 0; f < 4; ++f)
                #pragma unroll
                for (int q = 0; q < 4; ++q) {
                    float v0 = acc[pl][f][0][q], v1 = acc[pl][f][1][q];
                    s0 += v0; ss0 += v0 * v0; s1 += v1; ss1 += v1 * v1;
                }
        s0 += __shfl_xor(s0, 16); s0 += __shfl_xor(s0, 32);
        ss0 += __shfl_xor(ss0, 16); ss0 += __shfl_xor(ss0, 32);
        s1 += __shfl_xor(s1, 16); s1 += __shfl_xor(s1, 32);
        ss1 += __shfl_xor(ss1, 16); ss1 += __shfl_xor(ss1, 32);
        if (lane < 16) {
            s_red[(wv * 32 + 2 * row) * 2]         = s0;
            s_red[(wv * 32 + 2 * row) * 2 + 1]     = ss0;
            s_red[(wv * 32 + 2 * row + 1) * 2]     = s1;
            s_red[(wv * 32 + 2 * row + 1) * 2 + 1] = ss1;
        }
    }

    #pragma unroll
    for (int pl = 0; pl < 2; ++pl) {
        int zp = 2 * wv + pl;
        unsigned short* ob = outb
            + ((((size_t)b << 18) + ((size_t)(z0 + zp) << 12) + (y0 << 6) + x0) << 5)
            + (row << 1);
        #pragma unroll
        for (int f = 0; f < 4; ++f) {
            #pragma unroll
            for (int qq = 0; qq < 4; ++qq) {
                int u = g4 * 4 + qq;
                int yy = f * 2 + (u >> 3), xx = u & 7;
                unsigned pk = (unsigned)f2bf(acc[pl][f][0][qq])
                            | ((unsigned)f2bf(acc[pl][f][1][qq]) << 16);
                *(unsigned*)(ob + ((yy << 6) + xx) * 32) = pk;
            }
        }
    }

    __syncthreads();
    if (tid < 64) {
        int n = tid & 31, sel = tid >> 5;
        float tot = 0.f;
        #pragma unroll
        for (int w = 0; w < 8; ++w) tot += s_red[(w * 32 + n) * 2 + sel];
        atomicAdd(&raw_out[(b * 32 + n) * 2 + sel], tot);
    }
}

__global__ void stats_final_k(const float* __restrict__ raw, float* __restrict__ stats)
{
    int bc = threadIdx.x;   // 64
    float mean = raw[bc * 2] * (1.f / 262144.f);
    float var  = raw[bc * 2 + 1] * (1.f / 262144.f) - mean * mean;
    stats[bc * 2]     = mean;
    stats[bc * 2 + 1] = rsqrtf(var + EPS_F);
}

// ---------------------------------------------------------------------------
// ROI pooling GEMM with FUSED mask read: D[bc=64][r=96] += A[bc][s]*B[s][r].
// A = norm+relu(emb bf16 channels-last) transposed on load; B = raw f32 mask
// -> bf16 (each (r,s-chunk) read by exactly one block -> mask read ONCE).
// Per-ROI voxel-count partials via 16-lane shfl reduce -> cntp[blk][96].
// NPART blocks x 4 chunks x 128 s; dense partial tile -> part[blk][96][64].
// ---------------------------------------------------------------------------
__global__ __launch_bounds__(256)
void pool_mfma_k(const unsigned short* __restrict__ emb, const float* __restrict__ stats3,
                 const float* __restrict__ mask, float* __restrict__ part,
                 float* __restrict__ cntp)
{
    __shared__ unsigned short Ald[64 * 136];   // [bc][k=128] bf16
    __shared__ unsigned short Bld[96 * 136];   // [r][k=128] bf16
    __shared__ float s_ns[128];                // rs[64] | -m*rs[64]

    const int tid  = threadIdx.x;
    const int lane = tid & 63, wv = tid >> 6;
    const int row  = lane & 15, g4 = lane >> 4;

    if (tid < 64) {
        float m = stats3[tid * 2], rs = stats3[tid * 2 + 1];
        s_ns[tid]      = rs;
        s_ns[64 + tid] = -m * rs;
    }

    f32x4 acc[6] = {};
    float csum[6] = {};

    for (int ch = 0; ch < 4; ++ch) {
        const int s0 = (blockIdx.x * 4 + ch) << 7;
        __syncthreads();
        // stage A: channels-last bf16 -> normalized [bc][s] (transpose on load)
        for (int i = tid; i < 1024; i += 256) {
            int bb = i >> 9, v = (i >> 2) & 127, g = i & 3;
            const unsigned short* p = emb + (((size_t)bb << 18) + (size_t)(s0 + v)) * 32 + (g << 3);
            s16x8 rv = *(const s16x8*)p;
            #pragma unroll
            for (int j = 0; j < 8; ++j) {
                int bc = bb * 32 + (g << 3) + j;
                float vf = bf2f((unsigned short)rv[j]);
                float nv = fmaxf(0.f, fmaf(vf, s_ns[bc], s_ns[64 + bc]));
                Ald[bc * 136 + v] = f2bf(nv);
            }
        }
        // stage B: raw mask f32 -> bf16 (+ per-r count partials)
        #pragma unroll
        for (int k = 0; k < 6; ++k) {
            int i = tid + k * 256;
            int r = i >> 4, bs = i & 15;
            s16x8 vec = (s16x8)0;
            if (r < 90) {
                const float* mp = mask + (size_t)r * S_TOT + s0 + bs * 8;
                float4 m0 = *(const float4*)mp;
                float4 m1 = *(const float4*)(mp + 4);
                vec[0] = (m0.x != 0.f) ? (short)0x3F80 : (short)0;
                vec[1] = (m0.y != 0.f) ? (short)0x3F80 : (short)0;
                vec[2] = (m0.z != 0.f) ? (short)0x3F80 : (short)0;
                vec[3] = (m0.w != 0.f) ? (short)0x3F80 : (short)0;
                vec[4] = (m1.x != 0.f) ? (short)0x3F80 : (short)0;
                vec[5] = (m1.y != 0.f) ? (short)0x3F80 : (short)0;
                vec[6] = (m1.z != 0.f) ? (short)0x3F80 : (short)0;
                vec[7] = (m1.w != 0.f) ? (short)0x3F80 : (short)0;
                csum[k] += m0.x + m0.y + m0.z + m0.w + m1.x + m1.y + m1.z + m1.w;
            }
            *(s16x8*)&Bld[r * 136 + bs * 8] = vec;
        }
        __syncthreads();
        #pragma unroll
        for (int kk = 0; kk < 4; ++kk) {
            s16x8 a = *(const s16x8*)&Ald[(wv * 16 + row) * 136 + kk * 32 + g4 * 8];
            #pragma unroll
            for (int j = 0; j < 6; ++j) {
                s16x8 bb = *(const s16x8*)&Bld[(j * 16 + row) * 136 + kk * 32 + g4 * 8];
                acc[j] = __builtin_amdgcn_mfma_f32_16x16x32_bf16(a, bb, acc[j], 0, 0, 0);
            }
        }
    }
    // count partials: reduce over the 16-lane group sharing r
    #pragma unroll
    for (int k = 0; k < 6; ++k) {
        float c = csum[k];
        c += __shfl_xor(c, 1); c += __shfl_xor(c, 2);
        c += __shfl_xor(c, 4); c += __shfl_xor(c, 8);
        if ((tid & 15) == 0)
            cntp[(size_t)blockIdx.x * 96 + (tid >> 4) + k * 16] = c;
    }
    #pragma unroll
    for (int j = 0; j < 6; ++j) {
        *(f32x4*)&part[((size_t)blockIdx.x * 96 + j * 16 + row) * 64 + wv * 16 + g4 * 4]
            = acc[j];
    }
}

// ---------------------------------------------------------------------------
// Per-ROI partial+count reduction + gated MLP + projection. One block (64
// threads) per (b, r).
// ---------------------------------------------------------------------------
__global__ __launch_bounds__(64)
void mlp_k(const float* __restrict__ part, const float* __restrict__ cntp,
           const float* __restrict__ w1, const float* __restrict__ b1,
           const float* __restrict__ w2, const float* __restrict__ b2,
           const float* __restrict__ pw1, const float* __restrict__ pb1,
           const float* __restrict__ pw2, const float* __restrict__ pb2,
           float* __restrict__ out)
{
    const int r   = blockIdx.x % 90;
    const int b   = blockIdx.x / 90;
    const int tid = threadIdx.x;
    __shared__ float roi_s[32], h_s[64], f_s[32], p_s[64];

    // count total
    float cs = 0.f;
    for (int p = tid; p < NPART; p += 64) cs += cntp[(size_t)p * 96 + r];
    #pragma unroll
    for (int off = 32; off > 0; off >>= 1) cs += __shfl_xor(cs, off);

    {
        const int c = tid & 31, h = tid >> 5;
        const float* pp = part + ((size_t)(h * (NPART / 2)) * 96 + r) * 64 + b * 32 + c;
        float s = 0.f;
        #pragma unroll 4
        for (int p = 0; p < NPART / 2; ++p) s += pp[(size_t)p * 6144];
        s += __shfl_down(s, 32);
        if (tid < 32) roi_s[tid] = s / cs;
    }
    __syncthreads();
    {
        float s = b1[r * 64 + tid];
        for (int c = 0; c < 32; ++c)
            s = fmaf(roi_s[c], w1[(r * 32 + c) * 64 + tid], s);
        h_s[tid] = fmaxf(s, 0.f);
    }
    __syncthreads();
    if (tid < 32) {
        float s = b2[r * 32 + tid];
        for (int j = 0; j < 64; ++j)
            s = fmaf(h_s[j], w2[(r * 64 + j) * 32 + tid], s);
        float gate = 1.f / (1.f + expf(-s));
        f_s[tid] = gate * roi_s[tid];
    }
    __syncthreads();
    {
        float s = pb1[r * 64 + tid];
        for (int c = 0; c < 32; ++c)
            s = fmaf(f_s[c], pw1[(r * 32 + c) * 64 + tid], s);
        p_s[tid] = fmaxf(s, 0.f);
    }
    __syncthreads();
    if (tid < 32) {
        float s = pb2[r * 32 + tid];
        for (int j = 0; j < 64; ++j)
            s = fmaf(p_s[j], pw2[(r * 64 + j) * 32 + tid], s);
        out[((size_t)b * 90 + r) * 32 + tid] = s;
    }
}

// ---------------------------------------------------------------------------
extern "C" void kernel_launch(void* const* d_in, const int* in_sizes, int n_in,
                              void* d_out, int out_size, void* d_ws, size_t ws_size,
                              hipStream_t stream)
{
    const float* data    = (const float*)d_in[0];
    const float* mask    = (const float*)d_in[1];
    const float* conv0_w = (const float*)d_in[2];
    const float* convs_w = (const float*)d_in[4];
    const float* sw1 = (const float*)d_in[6];
    const float* sb1 = (const float*)d_in[7];
    const float* sw2 = (const float*)d_in[8];
    const float* sb2 = (const float*)d_in[9];
    const float* pw1 = (const float*)d_in[10];
    const float* pb1 = (const float*)d_in[11];
    const float* pw2 = (const float*)d_in[12];
    const float* pb2 = (const float*)d_in[13];
    float* out = (float*)d_out;

    float* ws = (float*)d_ws;
    unsigned short* bufA = (unsigned short*)ws;                  // 16,777,216 bf16
    unsigned short* bufB = (unsigned short*)(ws + 8388608);      // 16,777,216 bf16
    unsigned short* wpad = (unsigned short*)(ws + 16777216);     // 221,184 ushort
    float* raw   = ws + 16887808;        // 512
    float* stats = raw + 512;            // 512
    float* part  = ws + 17825792;        // NPART*96*64 = 3,145,728 floats
    float* cntp  = part + 3145728;       // NPART*96 = 49,152 floats

    hipMemsetAsync(raw, 0, 512 * sizeof(float), stream);
    prep_w_k<<<332, 256, 0, stream>>>(conv0_w, convs_w, wpad);

    // layer 0: data(fp32) -> bufA (bf16 channels-last), im2col-over-taps
    conv0_k<<<512, 512, 0, stream>>>(data, wpad, bufA, raw);
    stats_final_k<<<1, 64, 0, stream>>>(raw, stats);
    // layer 1: bufA -> bufB
    conv_slab_k<<<512, 512, 0, stream>>>(bufA, wpad + 55296, stats, bufB, raw + 128);
    stats_final_k<<<1, 64, 0, stream>>>(raw + 128, stats + 128);
    // layer 2: bufB -> bufA
    conv_slab_k<<<512, 512, 0, stream>>>(bufB, wpad + 2 * 55296, stats + 128, bufA, raw + 256);
    stats_final_k<<<1, 64, 0, stream>>>(raw + 256, stats + 256);
    // layer 3: bufA -> bufB
    conv_slab_k<<<512, 512, 0, stream>>>(bufA, wpad + 3 * 55296, stats + 256, bufB, raw + 384);
    stats_final_k<<<1, 64, 0, stream>>>(raw + 384, stats + 384);

    // ROI pooling GEMM with fused mask read -> dense partials + count partials
    pool_mfma_k<<<NPART, 256, 0, stream>>>(bufB, stats + 384, mask, part, cntp);

    // per-ROI partial reduction + MLPs
    mlp_k<<<180, 64, 0, stream>>>(part, cntp, sw1, sb1, sw2, sb2,
                                  pw1, pb1, pw2, pb2, out);
}